// Round 5
// baseline (166.770 us; speedup 1.0000x reference)
//
#include <hip/hip_runtime.h>
#include <math.h>

// Problem constants (fixed by reference setup_inputs)
constexpr int Bv = 8;
constexpr int Sv = 4096;
constexpr int Dv = 512;
constexpr int NCv = 64;           // S-chunks for pass-1 partials
constexpr int SCv = Sv / NCv;     // 64 rows per chunk
constexpr int Pv = 98;            // sampled partitions
constexpr int Kv = 6;             // max parts per partition
constexpr int MAXPv = 100;
constexpr int GPv = 14;           // partition groups in k23 (7 partitions each)
constexpr int PPGv = 7;           // partitions per group

// Native 4-float vector (layout-identical to float4) — required by
// __builtin_nontemporal_load, which rejects HIP_vector_type pointers.
typedef float v4f __attribute__((ext_vector_type(4)));

// Workspace layout (float offsets). No fences/tickets: round 2 measured
// per-block device-scope fences at ~100us total — kernel boundaries provide
// coherence for free.
constexpr size_t OFF_MPART = 0;
constexpr size_t OFF_ZPART = OFF_MPART + (size_t)Bv * NCv * Dv;
constexpr size_t OFF_TPART = OFF_ZPART + (size_t)Bv * NCv * Dv;
constexpr size_t OFF_HFULL = OFF_TPART + (size_t)Bv * NCv * Dv;  // [B]
constexpr size_t OFF_HSD   = OFF_HFULL + Bv;                     // [B] sum_d H_sd
constexpr size_t OFF_HBP   = OFF_HSD + Bv;                       // [B*P] sum_k H_pk

__device__ __forceinline__ float warpSum(float v) {
    for (int o = 32; o > 0; o >>= 1) v += __shfl_xor(v, o);
    return v;
}
__device__ __forceinline__ float warpMax(float v) {
    for (int o = 32; o > 0; o >>= 1) v = fmaxf(v, __shfl_xor(v, o));
    return v;
}
// 512-thread (8-wave) block reductions; red is shared float[8]; result to ALL.
__device__ __forceinline__ float blockSum512(float v, float* red) {
    float s = warpSum(v);
    int lane = threadIdx.x & 63, w = threadIdx.x >> 6;
    __syncthreads();
    if (lane == 0) red[w] = s;
    __syncthreads();
    return red[0] + red[1] + red[2] + red[3] + red[4] + red[5] + red[6] + red[7];
}
__device__ __forceinline__ float blockMax512(float v, float* red) {
    float s = warpMax(v);
    int lane = threadIdx.x & 63, w = threadIdx.x >> 6;
    __syncthreads();
    if (lane == 0) red[w] = s;
    __syncthreads();
    float m = red[0];
    for (int i = 1; i < 8; i++) m = fmaxf(m, red[i]);
    return m;
}

// Online softmax-stat update: (m, z, t) += element v
#define UPD(v, m, z, t)                                        \
    {                                                          \
        float vv = (v);                                        \
        if (vv > m) {                                          \
            float r = __expf(m - vv);                          \
            z = z * r + 1.0f;                                  \
            t = t * r + vv;                                    \
            m = vv;                                            \
        } else {                                               \
            float e_ = __expf(vv - m);                         \
            z += e_;                                           \
            t += e_ * vv;                                      \
        }                                                      \
    }

// Merge two stat triples. Safe when m == -inf.
__device__ __forceinline__ void mergeStats(float& m, float& z, float& t,
                                           float mb, float zb, float tb) {
    float nm = fmaxf(m, mb);
    float ra = __expf(m - nm);
    float rb = __expf(mb - nm);
    z = z * ra + zb * rb;
    t = t * ra + tb * rb;
    m = nm;
}

__device__ __forceinline__ float sigmoidf(float v) { return 1.0f / (1.0f + __expf(-v)); }

// ---------------------------------------------------------------------------
// Kernel 1: pass over x, per-(b,chunk,d) online stats (m, Z, T).
// Block = 512 threads: tid&127 -> d-group (float4), tid>>7 -> one of FOUR
// s-interleaves (chain length 16; 16 waves/CU for HBM latency hiding).
// Non-temporal loads keep L2 clean for the partials k23 re-reads.
// ---------------------------------------------------------------------------
__global__ __launch_bounds__(512) void k1_partial(const float* __restrict__ x,
                                                  float* __restrict__ ws) {
    int c = blockIdx.x;
    int b = blockIdx.y;
    int tid = threadIdx.x;
    int dg = tid & 127;
    int sl = tid >> 7;           // 0..3

    const v4f* xv = (const v4f*)x;
    float m0 = -INFINITY, m1 = -INFINITY, m2 = -INFINITY, m3 = -INFINITY;
    float z0 = 0.f, z1 = 0.f, z2 = 0.f, z3 = 0.f;
    float t0 = 0.f, t1 = 0.f, t2 = 0.f, t3 = 0.f;

    int sbase = c * SCv + sl;
#pragma unroll 4
    for (int i = 0; i < SCv / 4; i++) {
        int s = sbase + 4 * i;
        v4f v = __builtin_nontemporal_load(&xv[((size_t)b * Sv + s) * 128 + dg]);
        UPD(v.x, m0, z0, t0);
        UPD(v.y, m1, z1, t1);
        UPD(v.z, m2, z2, t2);
        UPD(v.w, m3, z3, t3);
    }

    // merge the four s-interleaves via LDS (two stages)
    __shared__ float smm[1024], smz[1024], smt[1024];
    // stage 1: sl=1 -> slot0 (for sl=0), sl=3 -> slot1 (for sl=2)
    if (sl == 1 || sl == 3) {
        int base = (sl >> 1) * 512 + dg * 4;
        smm[base + 0] = m0; smm[base + 1] = m1; smm[base + 2] = m2; smm[base + 3] = m3;
        smz[base + 0] = z0; smz[base + 1] = z1; smz[base + 2] = z2; smz[base + 3] = z3;
        smt[base + 0] = t0; smt[base + 1] = t1; smt[base + 2] = t2; smt[base + 3] = t3;
    }
    __syncthreads();
    if (sl == 0 || sl == 2) {
        int base = (sl >> 1) * 512 + dg * 4;
        mergeStats(m0, z0, t0, smm[base + 0], smz[base + 0], smt[base + 0]);
        mergeStats(m1, z1, t1, smm[base + 1], smz[base + 1], smt[base + 1]);
        mergeStats(m2, z2, t2, smm[base + 2], smz[base + 2], smt[base + 2]);
        mergeStats(m3, z3, t3, smm[base + 3], smz[base + 3], smt[base + 3]);
    }
    __syncthreads();
    // stage 2: sl=2 -> slot0 (for sl=0)
    if (sl == 2) {
        int base = dg * 4;
        smm[base + 0] = m0; smm[base + 1] = m1; smm[base + 2] = m2; smm[base + 3] = m3;
        smz[base + 0] = z0; smz[base + 1] = z1; smz[base + 2] = z2; smz[base + 3] = z3;
        smt[base + 0] = t0; smt[base + 1] = t1; smt[base + 2] = t2; smt[base + 3] = t3;
    }
    __syncthreads();
    if (sl == 0) {
        int base = dg * 4;
        mergeStats(m0, z0, t0, smm[base + 0], smz[base + 0], smt[base + 0]);
        mergeStats(m1, z1, t1, smm[base + 1], smz[base + 1], smt[base + 1]);
        mergeStats(m2, z2, t2, smm[base + 2], smz[base + 2], smt[base + 2]);
        mergeStats(m3, z3, t3, smm[base + 3], smz[base + 3], smt[base + 3]);

        size_t o = ((size_t)(b * NCv + c)) * 128 + dg;   // float4 index into [.,D]
        ((v4f*)(ws + OFF_MPART))[o] = (v4f){m0, m1, m2, m3};
        ((v4f*)(ws + OFF_ZPART))[o] = (v4f){z0, z1, z2, z3};
        ((v4f*)(ws + OFF_TPART))[o] = (v4f){t0, t1, t2, t3};
    }
}

// ---------------------------------------------------------------------------
// Kernel 23: fused combine + partitions. Grid (GP=14, B=8); each block
// redoes the 64-chunk combine for its b (L2-resident partials, registers
// only), g==0 blocks also emit H_sd/H_full; then each block handles 7
// partitions via wave-shuffle masked group reductions (no LDS atomics).
// ---------------------------------------------------------------------------
__global__ __launch_bounds__(512) void k23_parts(const void* __restrict__ masks,
                                                 float* __restrict__ ws) {
    int g = blockIdx.x;          // 0..13
    int b = blockIdx.y;
    int d = threadIdx.x;         // 0..511
    int lane = d & 63, w = d >> 6;

    const float* mp = ws + OFF_MPART;
    const float* zp = ws + OFF_ZPART;
    const float* tp = ws + OFF_TPART;

    // two independent 32-chunk merge chains, then a final merge (ILP)
    float ma = -INFINITY, za = 0.f, ta = 0.f;
    float mb2 = -INFINITY, zb2 = 0.f, tb2 = 0.f;
    for (int c = 0; c < NCv / 2; c++) {
        size_t ia = ((size_t)(b * NCv + c)) * Dv + d;
        size_t ib = ((size_t)(b * NCv + c + NCv / 2)) * Dv + d;
        mergeStats(ma, za, ta, mp[ia], zp[ia], tp[ia]);
        mergeStats(mb2, zb2, tb2, mp[ib], zp[ib], tp[ib]);
    }
    mergeStats(ma, za, ta, mb2, zb2, tb2);
    float xm = ma, e = za, t = ta;

    __shared__ float red[8];
    if (g == 0) {
        float hsd = xm + __logf(e) - t / e;      // per-(b,d) seq entropy
        float sum_h = blockSum512(hsd, red);
        float mbk = blockMax512(xm, red);
        float sc = __expf(xm - mbk);
        float zb = blockSum512(e * sc, red);
        float tb = blockSum512(t * sc, red);
        if (d == 0) {
            ws[OFF_HSD + b] = sum_h;
            ws[OFF_HFULL + b] = mbk + __logf(zb) - tb / zb;
        }
    }

    // mask dtype self-detect (uint8-packed bool vs int32): benign same-value race
    __shared__ int f;
    if (d == 0) f = 0;
    __syncthreads();
    if (((const unsigned int*)masks)[d] > 1u) f = 1;
    __syncthreads();
    int is_u8 = f;

    __shared__ float lmax[8 * Kv], lz[8 * Kv], lt[8 * Kv];
    __shared__ float gmax[Kv], hk[Kv];

    for (int i = 0; i < PPGv; i++) {
        int p = g * PPGv + i;

        int mk = 255;
        if (is_u8) {
            const unsigned char* mbyt = (const unsigned char*)masks;
            for (int k = 0; k < Kv; k++)
                if (mbyt[((size_t)p * Kv + k) * Dv + d]) { mk = k; break; }
        } else {
            const int* mint = (const int*)masks;
            for (int k = 0; k < Kv; k++)
                if (mint[((size_t)p * Kv + k) * Dv + d]) { mk = k; break; }
        }

        // phase 1: per-group max via masked wave-max + 8-wave LDS combine
        for (int k = 0; k < Kv; k++) {
            float cv = (mk == k) ? xm : -INFINITY;
            float wm = warpMax(cv);
            if (lane == 0) lmax[w * Kv + k] = wm;
        }
        __syncthreads();
        if (d < Kv) {
            float gm = lmax[d];
            for (int ww = 1; ww < 8; ww++) gm = fmaxf(gm, lmax[ww * Kv + d]);
            gmax[d] = gm;
        }
        __syncthreads();

        // phase 2: Z/T sums scaled to the group max
        int mks = (mk < Kv) ? mk : 0;
        float gm = gmax[mks];
        float s = __expf(xm - gm);
        float ez = e * s, tz = t * s;
        for (int k = 0; k < Kv; k++) {
            float cz = (mk == k) ? ez : 0.f;
            float ctv = (mk == k) ? tz : 0.f;
            float sz = warpSum(cz);
            float st = warpSum(ctv);
            if (lane == 0) { lz[w * Kv + k] = sz; lt[w * Kv + k] = st; }
        }
        __syncthreads();
        if (d < Kv) {
            float Z = 0.f, T = 0.f;
            for (int ww = 0; ww < 8; ww++) { Z += lz[ww * Kv + d]; T += lt[ww * Kv + d]; }
            float gmv = gmax[d];
            hk[d] = (gmv > -INFINITY) ? gmv + __logf(Z) - T / Z : 0.f;
        }
        __syncthreads();
        if (d == 0)
            ws[OFF_HBP + (size_t)b * Pv + p] =
                hk[0] + hk[1] + hk[2] + hk[3] + hk[4] + hk[5];
        __syncthreads();   // protect shared arrays before next partition
    }
}

// ---------------------------------------------------------------------------
// Kernel 4: combine 100 partition entropies, weighted min, MLP head.
// ---------------------------------------------------------------------------
__global__ __launch_bounds__(128) void k4_final(
    const float* __restrict__ es, const float* __restrict__ iw,
    const float* __restrict__ W1, const float* __restrict__ b1,
    const float* __restrict__ W2, const float* __restrict__ b2,
    const float* __restrict__ W3, const float* __restrict__ b3,
    const float* __restrict__ ws, float* __restrict__ out) {
    int tid = threadIdx.x;
    __shared__ float wgt[MAXPv];
    __shared__ float meanH_s;
    __shared__ float red[2];

    // mean(entropy_scales) over 512 elems
    float v = es[tid] + es[tid + 128] + es[tid + 256] + es[tid + 384];
    float s64 = warpSum(v);
    int lane = tid & 63, w = tid >> 6;
    if (lane == 0) red[w] = s64;
    __syncthreads();
    float es_mean = (red[0] + red[1]) * (1.0f / 512.0f);

    if (tid < Pv) {
        float s = 0.f;
        for (int b = 0; b < Bv; b++) s += ws[OFF_HBP + (size_t)b * Pv + tid];
        wgt[tid + 2] = (s * (1.0f / Bv)) * sigmoidf(iw[tid + 2]);
    } else if (tid == Pv) {          // h_whole
        float s = 0.f;
        for (int b = 0; b < Bv; b++) s += ws[OFF_HFULL + b];
        float mh = s * (1.0f / Bv);
        meanH_s = mh;
        wgt[0] = mh * sigmoidf(iw[0]);
    } else if (tid == Pv + 1) {      // h_single
        float s = 0.f;
        for (int b = 0; b < Bv; b++) s += ws[OFF_HSD + b];
        wgt[1] = (s * (1.0f / Bv)) * sigmoidf(iw[1]);
    }
    __syncthreads();

    if (tid == 0) {
        float mn = wgt[0];
        for (int i = 1; i < MAXPv; i++) mn = fminf(mn, wgt[i]);
        float raw = es_mean * meanH_s - mn;
        float z = fminf(fmaxf(raw * 0.1f, 0.0f), 1.0f);

        float h1[32];
        for (int j = 0; j < 32; j++) {
            float a = z * W1[j] + b1[j];
            h1[j] = a > 0.f ? a : 0.f;
        }
        float h2[16];
        for (int i = 0; i < 16; i++) {
            float a = b2[i];
            for (int j = 0; j < 32; j++) a += W2[i * 32 + j] * h1[j];
            h2[i] = a > 0.f ? a : 0.f;
        }
        float a = b3[0];
        for (int i = 0; i < 16; i++) a += W3[i] * h2[i];
        out[0] = sigmoidf(a);
    }
}

extern "C" void kernel_launch(void* const* d_in, const int* in_sizes, int n_in,
                              void* d_out, int out_size, void* d_ws, size_t ws_size,
                              hipStream_t stream) {
    const float* x  = (const float*)d_in[0];
    const float* es = (const float*)d_in[1];
    const float* iw = (const float*)d_in[2];
    const float* W1 = (const float*)d_in[3];
    const float* b1 = (const float*)d_in[4];
    const float* W2 = (const float*)d_in[5];
    const float* b2 = (const float*)d_in[6];
    const float* W3 = (const float*)d_in[7];
    const float* b3 = (const float*)d_in[8];
    const void* masks = d_in[9];
    float* ws = (float*)d_ws;
    float* out = (float*)d_out;

    k1_partial<<<dim3(NCv, Bv), dim3(512), 0, stream>>>(x, ws);
    k23_parts<<<dim3(GPv, Bv), dim3(512), 0, stream>>>(masks, ws);
    k4_final<<<dim3(1), dim3(128), 0, stream>>>(es, iw, W1, b1, W2, b2, W3, b3, ws, out);
}

// Round 6
// 152.170 us; speedup vs baseline: 1.0959x; 1.0959x over previous
//
#include <hip/hip_runtime.h>
#include <math.h>

// Problem constants (fixed by reference setup_inputs)
constexpr int Bv = 8;
constexpr int Sv = 4096;
constexpr int Dv = 512;
constexpr int NCv = 64;           // S-chunks for pass-1 partials
constexpr int SCv = Sv / NCv;     // 64 rows per chunk
constexpr int Pv = 98;            // sampled partitions
constexpr int Kv = 6;             // max parts per partition
constexpr int MAXPv = 100;

// Native 4-float vector (layout-identical to float4) — required by
// __builtin_nontemporal_load, which rejects HIP_vector_type pointers.
typedef float v4f __attribute__((ext_vector_type(4)));

// Workspace layout (float offsets). No fences/tickets (round-2 lesson: per-
// block device-scope fences cost ~100us total). No redundant per-block chunk
// combine (round-5 lesson: serial scalar-load merge chains are latency-bound,
// 50us at 112 blocks).
constexpr size_t OFF_MPART = 0;
constexpr size_t OFF_ZPART = OFF_MPART + (size_t)Bv * NCv * Dv;
constexpr size_t OFF_TPART = OFF_ZPART + (size_t)Bv * NCv * Dv;
constexpr size_t OFF_XMAX  = OFF_TPART + (size_t)Bv * NCv * Dv;  // [B,D]
constexpr size_t OFF_ED    = OFF_XMAX + (size_t)Bv * Dv;         // [B,D]
constexpr size_t OFF_TD    = OFF_ED   + (size_t)Bv * Dv;         // [B,D]
constexpr size_t OFF_HFULL = OFF_TD   + (size_t)Bv * Dv;         // [B]
constexpr size_t OFF_HSD   = OFF_HFULL + Bv;                     // [B]
constexpr size_t OFF_HBP   = OFF_HSD + Bv;                       // [B*P]

__device__ __forceinline__ float warpSum(float v) {
    for (int o = 32; o > 0; o >>= 1) v += __shfl_xor(v, o);
    return v;
}
__device__ __forceinline__ float warpMax(float v) {
    for (int o = 32; o > 0; o >>= 1) v = fmaxf(v, __shfl_xor(v, o));
    return v;
}
// 512-thread (8-wave) block reductions; red is shared float[8]; result to ALL.
__device__ __forceinline__ float blockSum512(float v, float* red) {
    float s = warpSum(v);
    int lane = threadIdx.x & 63, w = threadIdx.x >> 6;
    __syncthreads();
    if (lane == 0) red[w] = s;
    __syncthreads();
    return red[0] + red[1] + red[2] + red[3] + red[4] + red[5] + red[6] + red[7];
}
__device__ __forceinline__ float blockMax512(float v, float* red) {
    float s = warpMax(v);
    int lane = threadIdx.x & 63, w = threadIdx.x >> 6;
    __syncthreads();
    if (lane == 0) red[w] = s;
    __syncthreads();
    float m = red[0];
    for (int i = 1; i < 8; i++) m = fmaxf(m, red[i]);
    return m;
}

// Online softmax-stat update: (m, z, t) += element v
#define UPD(v, m, z, t)                                        \
    {                                                          \
        float vv = (v);                                        \
        if (vv > m) {                                          \
            float r = __expf(m - vv);                          \
            z = z * r + 1.0f;                                  \
            t = t * r + vv;                                    \
            m = vv;                                            \
        } else {                                               \
            float e_ = __expf(vv - m);                         \
            z += e_;                                           \
            t += e_ * vv;                                      \
        }                                                      \
    }

// Merge two stat triples. Safe when m == -inf.
__device__ __forceinline__ void mergeStats(float& m, float& z, float& t,
                                           float mb, float zb, float tb) {
    float nm = fmaxf(m, mb);
    float ra = __expf(m - nm);
    float rb = __expf(mb - nm);
    z = z * ra + zb * rb;
    t = t * ra + tb * rb;
    m = nm;
}

__device__ __forceinline__ float sigmoidf(float v) { return 1.0f / (1.0f + __expf(-v)); }

// ---------------------------------------------------------------------------
// Kernel 1: pass over x, per-(b,chunk,d) online stats (m, Z, T).
// Block = 512 threads: tid&127 -> d-group (float4), tid>>7 -> one of FOUR
// s-interleaves (chain length 16; 16 waves/CU for HBM latency hiding).
// Non-temporal loads: x is read exactly once.
// ---------------------------------------------------------------------------
__global__ __launch_bounds__(512) void k1_partial(const float* __restrict__ x,
                                                  float* __restrict__ ws) {
    int c = blockIdx.x;
    int b = blockIdx.y;
    int tid = threadIdx.x;
    int dg = tid & 127;
    int sl = tid >> 7;           // 0..3

    const v4f* xv = (const v4f*)x;
    float m0 = -INFINITY, m1 = -INFINITY, m2 = -INFINITY, m3 = -INFINITY;
    float z0 = 0.f, z1 = 0.f, z2 = 0.f, z3 = 0.f;
    float t0 = 0.f, t1 = 0.f, t2 = 0.f, t3 = 0.f;

    int sbase = c * SCv + sl;
#pragma unroll 4
    for (int i = 0; i < SCv / 4; i++) {
        int s = sbase + 4 * i;
        v4f v = __builtin_nontemporal_load(&xv[((size_t)b * Sv + s) * 128 + dg]);
        UPD(v.x, m0, z0, t0);
        UPD(v.y, m1, z1, t1);
        UPD(v.z, m2, z2, t2);
        UPD(v.w, m3, z3, t3);
    }

    // merge the four s-interleaves via LDS (two stages)
    __shared__ float smm[1024], smz[1024], smt[1024];
    if (sl == 1 || sl == 3) {
        int base = (sl >> 1) * 512 + dg * 4;
        smm[base + 0] = m0; smm[base + 1] = m1; smm[base + 2] = m2; smm[base + 3] = m3;
        smz[base + 0] = z0; smz[base + 1] = z1; smz[base + 2] = z2; smz[base + 3] = z3;
        smt[base + 0] = t0; smt[base + 1] = t1; smt[base + 2] = t2; smt[base + 3] = t3;
    }
    __syncthreads();
    if (sl == 0 || sl == 2) {
        int base = (sl >> 1) * 512 + dg * 4;
        mergeStats(m0, z0, t0, smm[base + 0], smz[base + 0], smt[base + 0]);
        mergeStats(m1, z1, t1, smm[base + 1], smz[base + 1], smt[base + 1]);
        mergeStats(m2, z2, t2, smm[base + 2], smz[base + 2], smt[base + 2]);
        mergeStats(m3, z3, t3, smm[base + 3], smz[base + 3], smt[base + 3]);
    }
    __syncthreads();
    if (sl == 2) {
        int base = dg * 4;
        smm[base + 0] = m0; smm[base + 1] = m1; smm[base + 2] = m2; smm[base + 3] = m3;
        smz[base + 0] = z0; smz[base + 1] = z1; smz[base + 2] = z2; smz[base + 3] = z3;
        smt[base + 0] = t0; smt[base + 1] = t1; smt[base + 2] = t2; smt[base + 3] = t3;
    }
    __syncthreads();
    if (sl == 0) {
        int base = dg * 4;
        mergeStats(m0, z0, t0, smm[base + 0], smz[base + 0], smt[base + 0]);
        mergeStats(m1, z1, t1, smm[base + 1], smz[base + 1], smt[base + 1]);
        mergeStats(m2, z2, t2, smm[base + 2], smz[base + 2], smt[base + 2]);
        mergeStats(m3, z3, t3, smm[base + 3], smz[base + 3], smt[base + 3]);

        size_t o = ((size_t)(b * NCv + c)) * 128 + dg;   // v4f index into [.,D]
        ((v4f*)(ws + OFF_MPART))[o] = (v4f){m0, m1, m2, m3};
        ((v4f*)(ws + OFF_ZPART))[o] = (v4f){z0, z1, z2, z3};
        ((v4f*)(ws + OFF_TPART))[o] = (v4f){t0, t1, t2, t3};
    }
}

// ---------------------------------------------------------------------------
// Kernel 2: combine chunk partials per (b,d) — ILP/coalescing-restructured.
// Grid (B=8), 512 threads = 128 d-float4-groups x 4 c-interleaves. Each
// thread merges 16 chunks via coalesced v4f loads (4 independent lanes),
// then the same 2-stage LDS merge as k1. Emits xmax/e/t[B,D], H_sd sum,
// and the full-flatten entropy H_full[b].
// ---------------------------------------------------------------------------
__global__ __launch_bounds__(512) void k2_combine(float* __restrict__ ws) {
    int b = blockIdx.x;
    int tid = threadIdx.x;
    int dg = tid & 127;
    int ci = tid >> 7;           // 0..3

    const v4f* mp = (const v4f*)(ws + OFF_MPART);
    const v4f* zp = (const v4f*)(ws + OFF_ZPART);
    const v4f* tp = (const v4f*)(ws + OFF_TPART);

    float m0 = -INFINITY, m1 = -INFINITY, m2 = -INFINITY, m3 = -INFINITY;
    float z0 = 0.f, z1 = 0.f, z2 = 0.f, z3 = 0.f;
    float t0 = 0.f, t1 = 0.f, t2 = 0.f, t3 = 0.f;

#pragma unroll 4
    for (int i = 0; i < NCv / 4; i++) {
        int c = ci + 4 * i;
        size_t o = ((size_t)(b * NCv + c)) * 128 + dg;
        v4f vm = mp[o], vz = zp[o], vt = tp[o];
        mergeStats(m0, z0, t0, vm.x, vz.x, vt.x);
        mergeStats(m1, z1, t1, vm.y, vz.y, vt.y);
        mergeStats(m2, z2, t2, vm.z, vz.z, vt.z);
        mergeStats(m3, z3, t3, vm.w, vz.w, vt.w);
    }

    // 2-stage LDS merge of the 4 c-interleaves
    __shared__ float smm[1024], smz[1024], smt[1024];
    __shared__ float red[8];
    if (ci == 1 || ci == 3) {
        int base = (ci >> 1) * 512 + dg * 4;
        smm[base + 0] = m0; smm[base + 1] = m1; smm[base + 2] = m2; smm[base + 3] = m3;
        smz[base + 0] = z0; smz[base + 1] = z1; smz[base + 2] = z2; smz[base + 3] = z3;
        smt[base + 0] = t0; smt[base + 1] = t1; smt[base + 2] = t2; smt[base + 3] = t3;
    }
    __syncthreads();
    if (ci == 0 || ci == 2) {
        int base = (ci >> 1) * 512 + dg * 4;
        mergeStats(m0, z0, t0, smm[base + 0], smz[base + 0], smt[base + 0]);
        mergeStats(m1, z1, t1, smm[base + 1], smz[base + 1], smt[base + 1]);
        mergeStats(m2, z2, t2, smm[base + 2], smz[base + 2], smt[base + 2]);
        mergeStats(m3, z3, t3, smm[base + 3], smz[base + 3], smt[base + 3]);
    }
    __syncthreads();
    if (ci == 2) {
        int base = dg * 4;
        smm[base + 0] = m0; smm[base + 1] = m1; smm[base + 2] = m2; smm[base + 3] = m3;
        smz[base + 0] = z0; smz[base + 1] = z1; smz[base + 2] = z2; smz[base + 3] = z3;
        smt[base + 0] = t0; smt[base + 1] = t1; smt[base + 2] = t2; smt[base + 3] = t3;
    }
    __syncthreads();

    float hsd_part = 0.f;        // per-thread contribution to sum_d H_sd
    float mloc = -INFINITY;      // per-thread max over its d's
    if (ci == 0) {
        int base = dg * 4;
        mergeStats(m0, z0, t0, smm[base + 0], smz[base + 0], smt[base + 0]);
        mergeStats(m1, z1, t1, smm[base + 1], smz[base + 1], smt[base + 1]);
        mergeStats(m2, z2, t2, smm[base + 2], smz[base + 2], smt[base + 2]);
        mergeStats(m3, z3, t3, smm[base + 3], smz[base + 3], smt[base + 3]);

        size_t o = (size_t)b * 128 + dg;
        ((v4f*)(ws + OFF_XMAX))[o] = (v4f){m0, m1, m2, m3};
        ((v4f*)(ws + OFF_ED))[o]   = (v4f){z0, z1, z2, z3};
        ((v4f*)(ws + OFF_TD))[o]   = (v4f){t0, t1, t2, t3};

        hsd_part = (m0 + __logf(z0) - t0 / z0) + (m1 + __logf(z1) - t1 / z1) +
                   (m2 + __logf(z2) - t2 / z2) + (m3 + __logf(z3) - t3 / z3);
        mloc = fmaxf(fmaxf(m0, m1), fmaxf(m2, m3));
    }

    // block-wide reductions (all threads participate; non-ci0 contribute
    // identity elements)
    float sum_h = blockSum512(hsd_part, red);
    float mb = blockMax512(mloc, red);
    float zc = 0.f, tc = 0.f;
    if (ci == 0) {
        float s0 = __expf(m0 - mb), s1 = __expf(m1 - mb);
        float s2 = __expf(m2 - mb), s3 = __expf(m3 - mb);
        zc = z0 * s0 + z1 * s1 + z2 * s2 + z3 * s3;
        tc = t0 * s0 + t1 * s1 + t2 * s2 + t3 * s3;
    }
    float zb = blockSum512(zc, red);
    float tb = blockSum512(tc, red);
    if (tid == 0) {
        ws[OFF_HSD + b] = sum_h;
        ws[OFF_HFULL + b] = mb + __logf(zb) - tb / zb;
    }
}

// ---------------------------------------------------------------------------
// Kernel 3: sampled partitions. One block per (p,b). Inline mask decode;
// group max + Z/T via wave-level masked shuffle reductions (no LDS atomics).
// Reads the tiny (48 KB) xmax/e/t arrays — L2-resident.
// ---------------------------------------------------------------------------
__global__ __launch_bounds__(512) void k3_parts(const void* __restrict__ masks,
                                                float* __restrict__ ws) {
    int p = blockIdx.x;
    int b = blockIdx.y;
    int d = threadIdx.x;
    int lane = d & 63, w = d >> 6;

    // mask dtype self-detect (uint8-packed bool vs int32): benign same-value race
    __shared__ int f;
    if (d == 0) f = 0;
    __syncthreads();
    if (((const unsigned int*)masks)[d] > 1u) f = 1;
    __syncthreads();

    int mk = 255;
    if (f) {
        const unsigned char* mbyt = (const unsigned char*)masks;
        for (int k = 0; k < Kv; k++)
            if (mbyt[((size_t)p * Kv + k) * Dv + d]) { mk = k; break; }
    } else {
        const int* mint = (const int*)masks;
        for (int k = 0; k < Kv; k++)
            if (mint[((size_t)p * Kv + k) * Dv + d]) { mk = k; break; }
    }

    float xm = ws[OFF_XMAX + (size_t)b * Dv + d];
    float e  = ws[OFF_ED   + (size_t)b * Dv + d];
    float t  = ws[OFF_TD   + (size_t)b * Dv + d];

    __shared__ float lmax[8 * Kv], lz[8 * Kv], lt[8 * Kv];
    __shared__ float gmax[Kv], hk[Kv];

    // phase 1: per-group max via masked wave-max + 8-wave LDS combine
    for (int k = 0; k < Kv; k++) {
        float cv = (mk == k) ? xm : -INFINITY;
        float wm = warpMax(cv);
        if (lane == 0) lmax[w * Kv + k] = wm;
    }
    __syncthreads();
    if (d < Kv) {
        float gm = lmax[d];
        for (int ww = 1; ww < 8; ww++) gm = fmaxf(gm, lmax[ww * Kv + d]);
        gmax[d] = gm;
    }
    __syncthreads();

    // phase 2: Z/T sums scaled to the group max
    int mks = (mk < Kv) ? mk : 0;
    float gm = gmax[mks];
    float s = __expf(xm - gm);
    float ez = e * s, tz = t * s;
    for (int k = 0; k < Kv; k++) {
        float cz = (mk == k) ? ez : 0.f;
        float ctv = (mk == k) ? tz : 0.f;
        float sz = warpSum(cz);
        float st = warpSum(ctv);
        if (lane == 0) { lz[w * Kv + k] = sz; lt[w * Kv + k] = st; }
    }
    __syncthreads();
    if (d < Kv) {
        float Z = 0.f, T = 0.f;
        for (int ww = 0; ww < 8; ww++) { Z += lz[ww * Kv + d]; T += lt[ww * Kv + d]; }
        float gmv = gmax[d];
        hk[d] = (gmv > -INFINITY) ? gmv + __logf(Z) - T / Z : 0.f;
    }
    __syncthreads();
    if (d == 0)
        ws[OFF_HBP + (size_t)b * Pv + p] =
            hk[0] + hk[1] + hk[2] + hk[3] + hk[4] + hk[5];
}

// ---------------------------------------------------------------------------
// Kernel 4: combine 100 partition entropies, weighted min, MLP head.
// ---------------------------------------------------------------------------
__global__ __launch_bounds__(128) void k4_final(
    const float* __restrict__ es, const float* __restrict__ iw,
    const float* __restrict__ W1, const float* __restrict__ b1,
    const float* __restrict__ W2, const float* __restrict__ b2,
    const float* __restrict__ W3, const float* __restrict__ b3,
    const float* __restrict__ ws, float* __restrict__ out) {
    int tid = threadIdx.x;
    __shared__ float wgt[MAXPv];
    __shared__ float meanH_s;
    __shared__ float red[2];

    // mean(entropy_scales) over 512 elems
    float v = es[tid] + es[tid + 128] + es[tid + 256] + es[tid + 384];
    float s64 = warpSum(v);
    int lane = tid & 63, w = tid >> 6;
    if (lane == 0) red[w] = s64;
    __syncthreads();
    float es_mean = (red[0] + red[1]) * (1.0f / 512.0f);

    if (tid < Pv) {
        float s = 0.f;
        for (int b = 0; b < Bv; b++) s += ws[OFF_HBP + (size_t)b * Pv + tid];
        wgt[tid + 2] = (s * (1.0f / Bv)) * sigmoidf(iw[tid + 2]);
    } else if (tid == Pv) {          // h_whole
        float s = 0.f;
        for (int b = 0; b < Bv; b++) s += ws[OFF_HFULL + b];
        float mh = s * (1.0f / Bv);
        meanH_s = mh;
        wgt[0] = mh * sigmoidf(iw[0]);
    } else if (tid == Pv + 1) {      // h_single
        float s = 0.f;
        for (int b = 0; b < Bv; b++) s += ws[OFF_HSD + b];
        wgt[1] = (s * (1.0f / Bv)) * sigmoidf(iw[1]);
    }
    __syncthreads();

    if (tid == 0) {
        float mn = wgt[0];
        for (int i = 1; i < MAXPv; i++) mn = fminf(mn, wgt[i]);
        float raw = es_mean * meanH_s - mn;
        float z = fminf(fmaxf(raw * 0.1f, 0.0f), 1.0f);

        float h1[32];
        for (int j = 0; j < 32; j++) {
            float a = z * W1[j] + b1[j];
            h1[j] = a > 0.f ? a : 0.f;
        }
        float h2[16];
        for (int i = 0; i < 16; i++) {
            float a = b2[i];
            for (int j = 0; j < 32; j++) a += W2[i * 32 + j] * h1[j];
            h2[i] = a > 0.f ? a : 0.f;
        }
        float a = b3[0];
        for (int i = 0; i < 16; i++) a += W3[i] * h2[i];
        out[0] = sigmoidf(a);
    }
}

extern "C" void kernel_launch(void* const* d_in, const int* in_sizes, int n_in,
                              void* d_out, int out_size, void* d_ws, size_t ws_size,
                              hipStream_t stream) {
    const float* x  = (const float*)d_in[0];
    const float* es = (const float*)d_in[1];
    const float* iw = (const float*)d_in[2];
    const float* W1 = (const float*)d_in[3];
    const float* b1 = (const float*)d_in[4];
    const float* W2 = (const float*)d_in[5];
    const float* b2 = (const float*)d_in[6];
    const float* W3 = (const float*)d_in[7];
    const float* b3 = (const float*)d_in[8];
    const void* masks = d_in[9];
    float* ws = (float*)d_ws;
    float* out = (float*)d_out;

    k1_partial<<<dim3(NCv, Bv), dim3(512), 0, stream>>>(x, ws);
    k2_combine<<<dim3(Bv), dim3(512), 0, stream>>>(ws);
    k3_parts<<<dim3(Pv, Bv), dim3(512), 0, stream>>>(masks, ws);
    k4_final<<<dim3(1), dim3(128), 0, stream>>>(es, iw, W1, b1, W2, b2, W3, b3, ws, out);
}